// Round 7
// baseline (59.832 us; speedup 1.0000x reference)
//
#include <hip/hip_runtime.h>
#include <math.h>

#define CDIM   862
#define NPAIR  (CDIM / 2)            // 431 float2 pairs per row
#define NRANK  8
#define KW     7
#define ROWS_PER_BLOCK 4
#define THREADS (ROWS_PER_BLOCK * 64)
#define NBLK   1440                  // persistent grid: 1440 blocks x 2 batches = 2880 row-batches
#define SROW   904                   // LDS row stride (floats): 4 pad + 862 + slack so prefetch needs no guards
#define LN_EPS 1e-5f
#define NJ     7                     // 6 full pair-slices + tail
#define TAILP  (NPAIR - 6 * 64)      // 47 pairs in the tail slice

// One wave owns one row; each lane owns element-pairs (2m, 2m+1), m = lane+64j.
// Persistent grid: each block handles 2 row-batches so all blocks are
// co-resident for the whole kernel (sustained ~70% occupancy, no launch tail).
// Window read as 5x ds_read_b64, double-buffered (unguarded prefetch: SROW has
// slack, garbage feeds only discarded tail lanes). GELU: tanh-sigmoid with
// rank-paired rcp (one v_rcp per 2 ranks).
__global__ __launch_bounds__(THREADS) void cvmc_kernel(
    const float* __restrict__ x,
    const float* __restrict__ Wup,
    const float* __restrict__ bup,
    const float* __restrict__ Wdown,
    const float* __restrict__ bdown,
    const float* __restrict__ gamma,
    const float* __restrict__ beta,
    float* __restrict__ out,
    int nrows)
{
    const int lane = threadIdx.x & 63;
    const int wv   = threadIdx.x >> 6;

    __shared__ float sx[ROWS_PER_BLOCK][SROW];   // sx[.][4+i] = x[i]

    // Uniform weights -> SGPR scalar loads.
    float wu[NRANK][KW];
    float bu[NRANK], wd[NRANK];
#pragma unroll
    for (int r = 0; r < NRANK; ++r) {
#pragma unroll
        for (int k = 0; k < KW; ++k) wu[r][k] = Wup[r * KW + k];
        bu[r] = bup[r];
        wd[r] = Wdown[r];
    }
    const float bd = bdown[0];

    const float C1 = -0.0713548162f;   // gelu(t) ~ t*sigmoid(1.5957691 t + 0.07135482 t^3)
    const float C0 = -1.5957691216f;

    float* s = sx[wv];
    const int nrb = (nrows + ROWS_PER_BLOCK - 1) / ROWS_PER_BLOCK;   // 2880

    for (int rb = blockIdx.x; rb < nrb; rb += NBLK) {
        const int row  = rb * ROWS_PER_BLOCK + wv;
        const bool live = (row < nrows);

        if (live) {
            const float* __restrict__ xr = x + (size_t)row * CDIM;
            for (int i = lane; i < NPAIR; i += 64) {
                float2 v = reinterpret_cast<const float2*>(xr)[i];
                *reinterpret_cast<float2*>(&s[4 + 2 * i]) = v;
            }
            if (lane < 4) {
                s[lane] = 0.0f;              // x[-4..-1]
                s[4 + CDIM + lane] = 0.0f;   // x[862..865]
            }
        }
        __syncthreads();

        const float2* sp = reinterpret_cast<const float2*>(s);

        float2 yv[NJ];
        float sum = 0.0f, sumsq = 0.0f;

        float2 wbuf[2][5];
        if (live) {
#pragma unroll
            for (int q = 0; q < 5; ++q) wbuf[0][q] = sp[lane + q];   // slice-0 window

#pragma unroll
            for (int j = 0; j < NJ; ++j) {
                const int cur = j & 1;
                const int nxt = cur ^ 1;
                // Unguarded prefetch: max pair index 63+64*6+4 = 451 < SROW/2=452.
                if (j + 1 < NJ) {
                    const int mn = lane + 64 * (j + 1);
#pragma unroll
                    for (int q = 0; q < 5; ++q) wbuf[nxt][q] = sp[mn + q];
                }
                if ((j < NJ - 1) || (lane < TAILP)) {
                    // w[i] = x[2m-4+i]; elem0 (c=2m) uses w[1..7], elem1 uses w[2..8].
                    float w[10];
#pragma unroll
                    for (int q = 0; q < 5; ++q) {
                        w[2 * q]     = wbuf[cur][q].x;
                        w[2 * q + 1] = wbuf[cur][q].y;
                    }
                    float acc0 = bd, acc1 = bd;
#pragma unroll
                    for (int rp = 0; rp < NRANK / 2; ++rp) {
                        const int ra = 2 * rp, rb2 = 2 * rp + 1;
                        float ta0 = bu[ra], ta1 = bu[ra];
                        float tb0 = bu[rb2], tb1 = bu[rb2];
#pragma unroll
                        for (int k = 0; k < KW; ++k) {
                            ta0 = fmaf(wu[ra][k],  w[k + 1], ta0);
                            ta1 = fmaf(wu[ra][k],  w[k + 2], ta1);
                            tb0 = fmaf(wu[rb2][k], w[k + 1], tb0);
                            tb1 = fmaf(wu[rb2][k], w[k + 2], tb1);
                        }
                        const float za0 = ta0 * fmaf(ta0 * ta0, C1, C0);
                        const float za1 = ta1 * fmaf(ta1 * ta1, C1, C0);
                        const float zb0 = tb0 * fmaf(tb0 * tb0, C1, C0);
                        const float zb1 = tb1 * fmaf(tb1 * tb1, C1, C0);
                        const float ua0 = 1.0f + __expf(za0);
                        const float ua1 = 1.0f + __expf(za1);
                        const float ub0 = 1.0f + __expf(zb0);
                        const float ub1 = 1.0f + __expf(zb1);
                        // wd_a*t_a/u_a + wd_b*t_b/u_b = (a_a*u_b + a_b*u_a)/(u_a*u_b)
                        const float r0 = __builtin_amdgcn_rcpf(ua0 * ub0);
                        const float r1 = __builtin_amdgcn_rcpf(ua1 * ub1);
                        const float aa0 = wd[ra] * ta0,  aa1 = wd[ra] * ta1;
                        const float ab0 = wd[rb2] * tb0, ab1 = wd[rb2] * tb1;
                        float n0 = aa0 * ub0; n0 = fmaf(ab0, ua0, n0);
                        float n1 = aa1 * ub1; n1 = fmaf(ab1, ua1, n1);
                        acc0 = fmaf(n0, r0, acc0);
                        acc1 = fmaf(n1, r1, acc1);
                    }
                    const float y0 = w[4] + acc0;   // x[2m]   + h
                    const float y1 = w[5] + acc1;   // x[2m+1] + h
                    yv[j] = make_float2(y0, y1);
                    sum += y0 + y1;
                    sumsq = fmaf(y0, y0, sumsq);
                    sumsq = fmaf(y1, y1, sumsq);
                }
            }
        }

        // In-wave butterfly: every lane ends with row totals.
#pragma unroll
        for (int off = 1; off < 64; off <<= 1) {
            sum   += __shfl_xor(sum, off, 64);
            sumsq += __shfl_xor(sumsq, off, 64);
        }

        if (live) {
            const float inv  = 1.0f / (float)CDIM;
            const float mu   = sum * inv;
            const float var  = fmaf(sumsq, inv, -mu * mu);
            const float rstd = rsqrtf(var + LN_EPS);

            float2* __restrict__ yr2 = reinterpret_cast<float2*>(out + (size_t)row * CDIM);
            const float2* g2 = reinterpret_cast<const float2*>(gamma);
            const float2* b2 = reinterpret_cast<const float2*>(beta);
#pragma unroll
            for (int j = 0; j < NJ; ++j) {
                if ((j < NJ - 1) || (lane < TAILP)) {
                    const int m = lane + 64 * j;
                    const float2 gv = g2[m];
                    const float2 bv = b2[m];
                    float2 o;
                    o.x = fmaf((yv[j].x - mu) * rstd, gv.x, bv.x);
                    o.y = fmaf((yv[j].y - mu) * rstd, gv.y, bv.y);
                    yr2[m] = o;
                }
            }
        }
        __syncthreads();   // batch separation before next staging overwrite
    }
}

extern "C" void kernel_launch(void* const* d_in, const int* in_sizes, int n_in,
                              void* d_out, int out_size, void* d_ws, size_t ws_size,
                              hipStream_t stream) {
    const float* x     = (const float*)d_in[0];
    const float* Wup   = (const float*)d_in[1];
    const float* bup   = (const float*)d_in[2];
    const float* Wdown = (const float*)d_in[3];
    const float* bdown = (const float*)d_in[4];
    const float* gamma = (const float*)d_in[5];
    const float* beta  = (const float*)d_in[6];
    float* out = (float*)d_out;

    const int nrows = out_size / CDIM;   // 11520
    cvmc_kernel<<<NBLK, THREADS, 0, stream>>>(x, Wup, bup, Wdown, bdown,
                                              gamma, beta, out, nrows);
}

// Round 8
// 47.729 us; speedup vs baseline: 1.2536x; 1.2536x over previous
//
#include <hip/hip_runtime.h>
#include <math.h>

#define CDIM   862
#define NPAIR  (CDIM / 2)            // 431 float2 pairs per row
#define NRANK  8
#define KW     7
#define ROWS_PER_BLOCK 2             // 128-thread blocks: 16 WG/CU slots -> up to 32 waves/CU
#define THREADS (ROWS_PER_BLOCK * 64)
#define SROW   904                   // LDS row stride (floats): 4 pad + 862 + slack, no prefetch guards
#define LN_EPS 1e-5f
#define NJ     7                     // 6 full pair-slices + tail
#define TAILP  (NPAIR - 6 * 64)      // 47 pairs in the tail slice

// One wave owns one row; each lane owns element-pairs (2m, 2m+1), m = lane+64j.
// Grid = nrows/2 exactly (11520/2 = 5760): no liveness guards anywhere.
// Window x[2m-4..2m+5] read as 5x ds_read_b64, double-buffered prefetch
// (unguarded: SROW slack feeds only discarded tail lanes). GELU: tanh-sigmoid
// with rank-paired rcp (one v_rcp per 2 ranks).
__global__ __launch_bounds__(THREADS) void cvmc_kernel(
    const float* __restrict__ x,
    const float* __restrict__ Wup,
    const float* __restrict__ bup,
    const float* __restrict__ Wdown,
    const float* __restrict__ bdown,
    const float* __restrict__ gamma,
    const float* __restrict__ beta,
    float* __restrict__ out)
{
    const int lane = threadIdx.x & 63;
    const int wv   = threadIdx.x >> 6;
    const int row  = blockIdx.x * ROWS_PER_BLOCK + wv;

    __shared__ float sx[ROWS_PER_BLOCK][SROW];   // sx[.][4+i] = x[i]

    // Uniform weights -> SGPR scalar loads.
    float wu[NRANK][KW];
    float bu[NRANK], wd[NRANK];
#pragma unroll
    for (int r = 0; r < NRANK; ++r) {
#pragma unroll
        for (int k = 0; k < KW; ++k) wu[r][k] = Wup[r * KW + k];
        bu[r] = bup[r];
        wd[r] = Wdown[r];
    }
    const float bd = bdown[0];

    const float C1 = -0.0713548162f;   // gelu(t) ~ t*sigmoid(1.5957691 t + 0.07135482 t^3)
    const float C0 = -1.5957691216f;

    float* s = sx[wv];

    {
        const float* __restrict__ xr = x + (size_t)row * CDIM;
        for (int i = lane; i < NPAIR; i += 64) {
            float2 v = reinterpret_cast<const float2*>(xr)[i];
            *reinterpret_cast<float2*>(&s[4 + 2 * i]) = v;
        }
        if (lane < 4) {
            s[lane] = 0.0f;              // x[-4..-1]
            s[4 + CDIM + lane] = 0.0f;   // x[862..865]
        }
    }
    __syncthreads();

    const float2* sp = reinterpret_cast<const float2*>(s);

    float2 yv[NJ];
    float sum = 0.0f, sumsq = 0.0f;

    float2 wbuf[2][5];
#pragma unroll
    for (int q = 0; q < 5; ++q) wbuf[0][q] = sp[lane + q];   // slice-0 window

#pragma unroll
    for (int j = 0; j < NJ; ++j) {
        const int cur = j & 1;
        const int nxt = cur ^ 1;
        // Unguarded prefetch: max pair index 63+64*6+4 = 451 < SROW/2 = 452.
        if (j + 1 < NJ) {
            const int mn = lane + 64 * (j + 1);
#pragma unroll
            for (int q = 0; q < 5; ++q) wbuf[nxt][q] = sp[mn + q];
        }
        if ((j < NJ - 1) || (lane < TAILP)) {
            // w[i] = x[2m-4+i]; elem0 (c=2m) uses w[1..7], elem1 uses w[2..8].
            float w[10];
#pragma unroll
            for (int q = 0; q < 5; ++q) {
                w[2 * q]     = wbuf[cur][q].x;
                w[2 * q + 1] = wbuf[cur][q].y;
            }
            float acc0 = bd, acc1 = bd;
#pragma unroll
            for (int rp = 0; rp < NRANK / 2; ++rp) {
                const int ra = 2 * rp, rb = 2 * rp + 1;
                float ta0 = bu[ra], ta1 = bu[ra];
                float tb0 = bu[rb], tb1 = bu[rb];
#pragma unroll
                for (int k = 0; k < KW; ++k) {
                    ta0 = fmaf(wu[ra][k], w[k + 1], ta0);
                    ta1 = fmaf(wu[ra][k], w[k + 2], ta1);
                    tb0 = fmaf(wu[rb][k], w[k + 1], tb0);
                    tb1 = fmaf(wu[rb][k], w[k + 2], tb1);
                }
                const float za0 = ta0 * fmaf(ta0 * ta0, C1, C0);
                const float za1 = ta1 * fmaf(ta1 * ta1, C1, C0);
                const float zb0 = tb0 * fmaf(tb0 * tb0, C1, C0);
                const float zb1 = tb1 * fmaf(tb1 * tb1, C1, C0);
                const float ua0 = 1.0f + __expf(za0);
                const float ua1 = 1.0f + __expf(za1);
                const float ub0 = 1.0f + __expf(zb0);
                const float ub1 = 1.0f + __expf(zb1);
                // wd_a*t_a/u_a + wd_b*t_b/u_b = (a_a*u_b + a_b*u_a)/(u_a*u_b)
                const float r0 = __builtin_amdgcn_rcpf(ua0 * ub0);
                const float r1 = __builtin_amdgcn_rcpf(ua1 * ub1);
                const float aa0 = wd[ra] * ta0, aa1 = wd[ra] * ta1;
                const float ab0 = wd[rb] * tb0, ab1 = wd[rb] * tb1;
                float n0 = aa0 * ub0; n0 = fmaf(ab0, ua0, n0);
                float n1 = aa1 * ub1; n1 = fmaf(ab1, ua1, n1);
                acc0 = fmaf(n0, r0, acc0);
                acc1 = fmaf(n1, r1, acc1);
            }
            const float y0 = w[4] + acc0;   // x[2m]   + h
            const float y1 = w[5] + acc1;   // x[2m+1] + h
            yv[j] = make_float2(y0, y1);
            sum += y0 + y1;
            sumsq = fmaf(y0, y0, sumsq);
            sumsq = fmaf(y1, y1, sumsq);
        }
    }

    // In-wave butterfly: every lane ends with row totals. No LDS, no barrier.
#pragma unroll
    for (int off = 1; off < 64; off <<= 1) {
        sum   += __shfl_xor(sum, off, 64);
        sumsq += __shfl_xor(sumsq, off, 64);
    }

    {
        const float inv  = 1.0f / (float)CDIM;
        const float mu   = sum * inv;
        const float var  = fmaf(sumsq, inv, -mu * mu);
        const float rstd = rsqrtf(var + LN_EPS);

        float2* __restrict__ yr2 = reinterpret_cast<float2*>(out + (size_t)row * CDIM);
        const float2* g2 = reinterpret_cast<const float2*>(gamma);
        const float2* b2 = reinterpret_cast<const float2*>(beta);
#pragma unroll
        for (int j = 0; j < NJ; ++j) {
            if ((j < NJ - 1) || (lane < TAILP)) {
                const int m = lane + 64 * j;
                const float2 gv = g2[m];
                const float2 bv = b2[m];
                float2 o;
                o.x = fmaf((yv[j].x - mu) * rstd, gv.x, bv.x);
                o.y = fmaf((yv[j].y - mu) * rstd, gv.y, bv.y);
                yr2[m] = o;
            }
        }
    }
}

extern "C" void kernel_launch(void* const* d_in, const int* in_sizes, int n_in,
                              void* d_out, int out_size, void* d_ws, size_t ws_size,
                              hipStream_t stream) {
    const float* x     = (const float*)d_in[0];
    const float* Wup   = (const float*)d_in[1];
    const float* bup   = (const float*)d_in[2];
    const float* Wdown = (const float*)d_in[3];
    const float* bdown = (const float*)d_in[4];
    const float* gamma = (const float*)d_in[5];
    const float* beta  = (const float*)d_in[6];
    float* out = (float*)d_out;

    const int nrows = out_size / CDIM;           // 11520 (divisible by 2)
    const int nblk  = nrows / ROWS_PER_BLOCK;    // 5760
    cvmc_kernel<<<nblk, THREADS, 0, stream>>>(x, Wup, bup, Wdown, bdown,
                                              gamma, beta, out);
}

// Round 9
// 47.641 us; speedup vs baseline: 1.2559x; 1.0019x over previous
//
#include <hip/hip_runtime.h>
#include <math.h>

#define CDIM   862
#define NPAIR  (CDIM / 2)            // 431 float2 pairs per row
#define NRANK  8
#define KW     7
#define ROWS_PER_BLOCK 2             // 128-thread blocks
#define THREADS (ROWS_PER_BLOCK * 64)
#define SROW   904                   // LDS row stride (floats): 4 pad + 862 + slack, no prefetch guards
#define LN_EPS 1e-5f
#define NJ     7                     // 6 full pair-slices + tail
#define TAILP  (NPAIR - 6 * 64)      // 47 pairs in the tail slice

// One wave owns one row; each lane owns element-pairs (2m, 2m+1), m = lane+64j.
// Grid = nrows/2 exactly (5760): no liveness guards. Window x[2m-4..2m+5] read
// as 5x ds_read_b64, double-buffered prefetch. GELU: tanh-sigmoid with
// rank-paired rcp (one v_rcp per 2 ranks).
// __launch_bounds__(128, 4): min 4 waves/EU -> VGPR cap 128. Round 8 showed
// VGPR=36 (compiler packed for max occupancy), which serialized the 16
// independent conv/GELU chains; this gives the scheduler register room for
// ILP while guaranteeing the current 16 waves/CU.
__global__ __launch_bounds__(THREADS, 4) void cvmc_kernel(
    const float* __restrict__ x,
    const float* __restrict__ Wup,
    const float* __restrict__ bup,
    const float* __restrict__ Wdown,
    const float* __restrict__ bdown,
    const float* __restrict__ gamma,
    const float* __restrict__ beta,
    float* __restrict__ out)
{
    const int lane = threadIdx.x & 63;
    const int wv   = threadIdx.x >> 6;
    const int row  = blockIdx.x * ROWS_PER_BLOCK + wv;

    __shared__ float sx[ROWS_PER_BLOCK][SROW];   // sx[.][4+i] = x[i]

    // Uniform weights -> SGPR scalar loads.
    float wu[NRANK][KW];
    float bu[NRANK], wd[NRANK];
#pragma unroll
    for (int r = 0; r < NRANK; ++r) {
#pragma unroll
        for (int k = 0; k < KW; ++k) wu[r][k] = Wup[r * KW + k];
        bu[r] = bup[r];
        wd[r] = Wdown[r];
    }
    const float bd = bdown[0];

    const float C1 = -0.0713548162f;   // gelu(t) ~ t*sigmoid(1.5957691 t + 0.07135482 t^3)
    const float C0 = -1.5957691216f;

    float* s = sx[wv];

    {
        const float* __restrict__ xr = x + (size_t)row * CDIM;
        for (int i = lane; i < NPAIR; i += 64) {
            float2 v = reinterpret_cast<const float2*>(xr)[i];
            *reinterpret_cast<float2*>(&s[4 + 2 * i]) = v;
        }
        if (lane < 4) {
            s[lane] = 0.0f;              // x[-4..-1]
            s[4 + CDIM + lane] = 0.0f;   // x[862..865]
        }
    }
    __syncthreads();

    const float2* sp = reinterpret_cast<const float2*>(s);

    float2 yv[NJ];
    float sum = 0.0f, sumsq = 0.0f;

    float2 wbuf[2][5];
#pragma unroll
    for (int q = 0; q < 5; ++q) wbuf[0][q] = sp[lane + q];   // slice-0 window

#pragma unroll
    for (int j = 0; j < NJ; ++j) {
        const int cur = j & 1;
        const int nxt = cur ^ 1;
        // Unguarded prefetch: max pair index 63+64*6+4 = 451 < SROW/2 = 452.
        if (j + 1 < NJ) {
            const int mn = lane + 64 * (j + 1);
#pragma unroll
            for (int q = 0; q < 5; ++q) wbuf[nxt][q] = sp[mn + q];
        }
        if ((j < NJ - 1) || (lane < TAILP)) {
            // w[i] = x[2m-4+i]; elem0 (c=2m) uses w[1..7], elem1 uses w[2..8].
            float w[10];
#pragma unroll
            for (int q = 0; q < 5; ++q) {
                w[2 * q]     = wbuf[cur][q].x;
                w[2 * q + 1] = wbuf[cur][q].y;
            }
            float acc0 = bd, acc1 = bd;
#pragma unroll
            for (int rp = 0; rp < NRANK / 2; ++rp) {
                const int ra = 2 * rp, rb = 2 * rp + 1;
                float ta0 = bu[ra], ta1 = bu[ra];
                float tb0 = bu[rb], tb1 = bu[rb];
#pragma unroll
                for (int k = 0; k < KW; ++k) {
                    ta0 = fmaf(wu[ra][k], w[k + 1], ta0);
                    ta1 = fmaf(wu[ra][k], w[k + 2], ta1);
                    tb0 = fmaf(wu[rb][k], w[k + 1], tb0);
                    tb1 = fmaf(wu[rb][k], w[k + 2], tb1);
                }
                const float za0 = ta0 * fmaf(ta0 * ta0, C1, C0);
                const float za1 = ta1 * fmaf(ta1 * ta1, C1, C0);
                const float zb0 = tb0 * fmaf(tb0 * tb0, C1, C0);
                const float zb1 = tb1 * fmaf(tb1 * tb1, C1, C0);
                const float ua0 = 1.0f + __expf(za0);
                const float ua1 = 1.0f + __expf(za1);
                const float ub0 = 1.0f + __expf(zb0);
                const float ub1 = 1.0f + __expf(zb1);
                // wd_a*t_a/u_a + wd_b*t_b/u_b = (a_a*u_b + a_b*u_a)/(u_a*u_b)
                const float r0 = __builtin_amdgcn_rcpf(ua0 * ub0);
                const float r1 = __builtin_amdgcn_rcpf(ua1 * ub1);
                const float aa0 = wd[ra] * ta0, aa1 = wd[ra] * ta1;
                const float ab0 = wd[rb] * tb0, ab1 = wd[rb] * tb1;
                float n0 = aa0 * ub0; n0 = fmaf(ab0, ua0, n0);
                float n1 = aa1 * ub1; n1 = fmaf(ab1, ua1, n1);
                acc0 = fmaf(n0, r0, acc0);
                acc1 = fmaf(n1, r1, acc1);
            }
            const float y0 = w[4] + acc0;   // x[2m]   + h
            const float y1 = w[5] + acc1;   // x[2m+1] + h
            yv[j] = make_float2(y0, y1);
            sum += y0 + y1;
            sumsq = fmaf(y0, y0, sumsq);
            sumsq = fmaf(y1, y1, sumsq);
        }
    }

    // In-wave butterfly: every lane ends with row totals. No LDS, no barrier.
#pragma unroll
    for (int off = 1; off < 64; off <<= 1) {
        sum   += __shfl_xor(sum, off, 64);
        sumsq += __shfl_xor(sumsq, off, 64);
    }

    {
        const float inv  = 1.0f / (float)CDIM;
        const float mu   = sum * inv;
        const float var  = fmaf(sumsq, inv, -mu * mu);
        const float rstd = rsqrtf(var + LN_EPS);

        float2* __restrict__ yr2 = reinterpret_cast<float2*>(out + (size_t)row * CDIM);
        const float2* g2 = reinterpret_cast<const float2*>(gamma);
        const float2* b2 = reinterpret_cast<const float2*>(beta);
#pragma unroll
        for (int j = 0; j < NJ; ++j) {
            if ((j < NJ - 1) || (lane < TAILP)) {
                const int m = lane + 64 * j;
                const float2 gv = g2[m];
                const float2 bv = b2[m];
                float2 o;
                o.x = fmaf((yv[j].x - mu) * rstd, gv.x, bv.x);
                o.y = fmaf((yv[j].y - mu) * rstd, gv.y, bv.y);
                yr2[m] = o;
            }
        }
    }
}

extern "C" void kernel_launch(void* const* d_in, const int* in_sizes, int n_in,
                              void* d_out, int out_size, void* d_ws, size_t ws_size,
                              hipStream_t stream) {
    const float* x     = (const float*)d_in[0];
    const float* Wup   = (const float*)d_in[1];
    const float* bup   = (const float*)d_in[2];
    const float* Wdown = (const float*)d_in[3];
    const float* bdown = (const float*)d_in[4];
    const float* gamma = (const float*)d_in[5];
    const float* beta  = (const float*)d_in[6];
    float* out = (float*)d_out;

    const int nrows = out_size / CDIM;           // 11520 (divisible by 2)
    const int nblk  = nrows / ROWS_PER_BLOCK;    // 5760
    cvmc_kernel<<<nblk, THREADS, 0, stream>>>(x, Wup, bup, Wdown, bdown,
                                              gamma, beta, out);
}

// Round 10
// 42.214 us; speedup vs baseline: 1.4173x; 1.1286x over previous
//
#include <hip/hip_runtime.h>
#include <math.h>

#define CDIM   862
#define NRANK  8
#define KW     7
#define ROWS_PER_BLOCK 4
#define THREADS (ROWS_PER_BLOCK * 64)
#define LN_EPS 1e-5f
#define EPL    14            // elements per lane: 62 lanes cover 862 (lane 61 partial)
#define PPL    (EPL / 2)     // 7 output float2 pairs per lane
#define NQ     11            // window float2 loads per lane: x[14i-4 .. 14i+17]
#define MAXPAIR 430          // last valid float2 pair index in a row (862/2 - 1)

// One wave = one row. Lane i owns elements [14i, 14i+13]; its conv windows
// need x[14i-4 .. 14i+17] = 11 float2 GLOBAL loads (8B-aligned, contiguous
// across lanes) held in 22 registers. No LDS, no barrier, no repack: all 14
// elements compute from registers. Halo zeros + row tail handled by index
// clamp + value masks. GELU math identical to rounds 6-9 (tanh-sigmoid,
// rank-paired rcp) -> absmax must match 0.03125.
__global__ __launch_bounds__(THREADS) void cvmc_kernel(
    const float* __restrict__ x,
    const float* __restrict__ Wup,
    const float* __restrict__ bup,
    const float* __restrict__ Wdown,
    const float* __restrict__ bdown,
    const float* __restrict__ gamma,
    const float* __restrict__ beta,
    float* __restrict__ out)
{
    const int lane = threadIdx.x & 63;
    const int wv   = threadIdx.x >> 6;
    const int row  = blockIdx.x * ROWS_PER_BLOCK + wv;

    // Uniform weights -> SGPR scalar loads.
    float wu[NRANK][KW];
    float bu[NRANK], wd[NRANK];
#pragma unroll
    for (int r = 0; r < NRANK; ++r) {
#pragma unroll
        for (int k = 0; k < KW; ++k) wu[r][k] = Wup[r * KW + k];
        bu[r] = bup[r];
        wd[r] = Wdown[r];
    }
    const float bd = bdown[0];

    const float C1 = -0.0713548162f;   // gelu(t) ~ t*sigmoid(1.5957691 t + 0.07135482 t^3)
    const float C0 = -1.5957691216f;

    const float2* __restrict__ xp = reinterpret_cast<const float2*>(x + (size_t)row * CDIM);

    // Load the lane's 22-float window into registers (indices static after unroll).
    float w[2 * NQ];
#pragma unroll
    for (int q = 0; q < NQ; ++q) {
        int pi = 7 * lane - 2 + q;                 // float2 pair index (may be OOB)
        int pc = pi < 0 ? 0 : (pi > MAXPAIR ? MAXPAIR : pi);
        float2 v = xp[pc];
        // Left halo x[-4..-1]: lane 0, q<2. Right halo x[862..]: lane 61, q>=6.
        if (q < 2)  { if (lane == 0)  { v.x = 0.0f; v.y = 0.0f; } }
        if (q >= 6) { if (lane == 61) { v.x = 0.0f; v.y = 0.0f; } }
        w[2 * q]     = v.x;
        w[2 * q + 1] = v.y;
    }

    float2 yv[PPL];
    float sum = 0.0f, sumsq = 0.0f;

#pragma unroll
    for (int pe = 0; pe < PPL; ++pe) {
        const int ce = EPL * lane + 2 * pe;        // global element index of y0
        const bool valid = (ce < CDIM);            // pairs are never split (862 even)
        // element e=2pe window = w[2pe+1 .. 2pe+7]; e+1 uses w[2pe+2 .. 2pe+8]
        const int f = 2 * pe;
        float acc0 = bd, acc1 = bd;
#pragma unroll
        for (int rp = 0; rp < NRANK / 2; ++rp) {
            const int ra = 2 * rp, rb = 2 * rp + 1;
            float ta0 = bu[ra], ta1 = bu[ra];
            float tb0 = bu[rb], tb1 = bu[rb];
#pragma unroll
            for (int k = 0; k < KW; ++k) {
                ta0 = fmaf(wu[ra][k], w[f + k + 1], ta0);
                ta1 = fmaf(wu[ra][k], w[f + k + 2], ta1);
                tb0 = fmaf(wu[rb][k], w[f + k + 1], tb0);
                tb1 = fmaf(wu[rb][k], w[f + k + 2], tb1);
            }
            const float za0 = ta0 * fmaf(ta0 * ta0, C1, C0);
            const float za1 = ta1 * fmaf(ta1 * ta1, C1, C0);
            const float zb0 = tb0 * fmaf(tb0 * tb0, C1, C0);
            const float zb1 = tb1 * fmaf(tb1 * tb1, C1, C0);
            const float ua0 = 1.0f + __expf(za0);
            const float ua1 = 1.0f + __expf(za1);
            const float ub0 = 1.0f + __expf(zb0);
            const float ub1 = 1.0f + __expf(zb1);
            // wd_a*t_a/u_a + wd_b*t_b/u_b = (a_a*u_b + a_b*u_a)/(u_a*u_b)
            const float r0 = __builtin_amdgcn_rcpf(ua0 * ub0);
            const float r1 = __builtin_amdgcn_rcpf(ua1 * ub1);
            const float aa0 = wd[ra] * ta0, aa1 = wd[ra] * ta1;
            const float ab0 = wd[rb] * tb0, ab1 = wd[rb] * tb1;
            float n0 = aa0 * ub0; n0 = fmaf(ab0, ua0, n0);
            float n1 = aa1 * ub1; n1 = fmaf(ab1, ua1, n1);
            acc0 = fmaf(n0, r0, acc0);
            acc1 = fmaf(n1, r1, acc1);
        }
        float y0 = w[f + 4] + acc0;   // x[ce]   + h
        float y1 = w[f + 5] + acc1;   // x[ce+1] + h
        if (!valid) { y0 = 0.0f; y1 = 0.0f; }      // tail lanes contribute 0
        yv[pe] = make_float2(y0, y1);
        sum += y0 + y1;
        sumsq = fmaf(y0, y0, sumsq);
        sumsq = fmaf(y1, y1, sumsq);
    }

    // In-wave butterfly: every lane ends with row totals. No LDS, no barrier.
#pragma unroll
    for (int off = 1; off < 64; off <<= 1) {
        sum   += __shfl_xor(sum, off, 64);
        sumsq += __shfl_xor(sumsq, off, 64);
    }

    {
        const float inv  = 1.0f / (float)CDIM;
        const float mu   = sum * inv;
        const float var  = fmaf(sumsq, inv, -mu * mu);
        const float rstd = rsqrtf(var + LN_EPS);

        float2* __restrict__ yr2 = reinterpret_cast<float2*>(out + (size_t)row * CDIM);
        const float2* __restrict__ g2 = reinterpret_cast<const float2*>(gamma);
        const float2* __restrict__ b2 = reinterpret_cast<const float2*>(beta);
#pragma unroll
        for (int pe = 0; pe < PPL; ++pe) {
            const int ce = EPL * lane + 2 * pe;
            if (ce < CDIM) {
                const int m = 7 * lane + pe;       // pair index in row
                const float2 gv = g2[m];
                const float2 bv = b2[m];
                float2 o;
                o.x = fmaf((yv[pe].x - mu) * rstd, gv.x, bv.x);
                o.y = fmaf((yv[pe].y - mu) * rstd, gv.y, bv.y);
                yr2[m] = o;
            }
        }
    }
}

extern "C" void kernel_launch(void* const* d_in, const int* in_sizes, int n_in,
                              void* d_out, int out_size, void* d_ws, size_t ws_size,
                              hipStream_t stream) {
    const float* x     = (const float*)d_in[0];
    const float* Wup   = (const float*)d_in[1];
    const float* bup   = (const float*)d_in[2];
    const float* Wdown = (const float*)d_in[3];
    const float* bdown = (const float*)d_in[4];
    const float* gamma = (const float*)d_in[5];
    const float* beta  = (const float*)d_in[6];
    float* out = (float*)d_out;

    const int nrows = out_size / CDIM;                 // 11520 (divisible by 4)
    const int nblk  = nrows / ROWS_PER_BLOCK;          // 2880
    cvmc_kernel<<<nblk, THREADS, 0, stream>>>(x, Wup, bup, Wdown, bdown,
                                              gamma, beta, out);
}